// Round 1
// baseline (368.092 us; speedup 1.0000x reference)
//
#include <hip/hip_runtime.h>
#include <hip/hip_bf16.h>

// GCN 2-layer forward on gfx950 — direct-atomic CSR, group-per-row packed
// fp16 gathers (no cross-lane reduction), fused fp16-MFMA MLP.
//
//   xh = fp16(dinv ⊙ x)            (row N = zeros, the OOB target; 128B rows)
//   t  = fp16( dinv[d] * Σ_{s∈csr[d]} xh[s] )     (gather, self-inclusive)
//   h  = relu(t W1 + b1)   [MFMA, C-frags in regs]
//   yh = fp16(dinv ⊙ (h W2))  — COMPACT 80B rows (40 halves, no pad)
//   out[d] = dinv[d] * Σ yh[s] + b2               (gather)
//
// R12: (a) radix-partition CSR (5 kernels, 2 passes over ei + 6.4MB tmp
// roundtrip, two 1-block scans) -> direct atomic build (zero/deg/alloc/fill,
// 27MB traffic, no serial scans). ssrc now stores NODE INDICES; each gather
// scales to its row stride. (b) yh compacted 128B->80B rows: k_mlp stops
// writing 4.8MB of pad zeros, gather2 footprint 12.8->8MB (L2 hit up).
// (c) nontemporal loads/stores on streaming operands (ei, ssrc, th, out, x)
// so streams stop evicting the gather tables from per-XCD L2.
// Memory floor (R7/R8 A/B): ~31us/gather at 89MB fetch — (b)+(c) attack the
// fetch, not the floor formula.

static constexpr int FIN = 64;
static constexpr int HID = 128;
static constexpr int CLS = 40;

typedef _Float16 half8 __attribute__((ext_vector_type(8)));
typedef _Float16 half4v __attribute__((ext_vector_type(4)));
typedef _Float16 half2v __attribute__((ext_vector_type(2)));
typedef float floatx4 __attribute__((ext_vector_type(4)));

// ---------------- CSR build: direct global atomics ----------------

// Zero the degree counters, the allocator cursor, and the OOB zero rows.
__global__ __launch_bounds__(256) void kZ(int* __restrict__ cnt,
                                          int* __restrict__ gcur,
                                          _Float16* __restrict__ xh,
                                          _Float16* __restrict__ yh, int N) {
    const int i = blockIdx.x * 256 + threadIdx.x;
    if (i < N) cnt[i] = 0;
    if (blockIdx.x == 0) {
        if (threadIdx.x == 0) *gcur = 0;
        if (threadIdx.x < 64) xh[(size_t)N * 64 + threadIdx.x] = (_Float16)0;
        if (threadIdx.x < 40) yh[(size_t)N * 40 + threadIdx.x] = (_Float16)0;
    }
}

__global__ __launch_bounds__(256) void k_deg(const int* __restrict__ dst,
                                             int* __restrict__ cnt, int E) {
    const int e = blockIdx.x * 256 + threadIdx.x;
    if (e < E) {
        const int d = __builtin_nontemporal_load(&dst[e]);
        atomicAdd(&cnt[d], 1);
    }
}

// Per-block scan + one atomicAdd on the global cursor: region placement is
// arbitrary (gathers only need [rstart, rstart+cnt) disjoint). Also writes
// dinv, the self-loop entry, and the fill cursor.
__global__ __launch_bounds__(256) void k_alloc(int* __restrict__ cnt,
                                               int* __restrict__ cur,
                                               int* __restrict__ rstart,
                                               float* __restrict__ dinv,
                                               int* __restrict__ ssrc,
                                               int* __restrict__ gcur, int N) {
    __shared__ int sd[256];
    __shared__ int sbase;
    const int tid = threadIdx.x;
    const int node = blockIdx.x * 256 + tid;
    const int deg = (node < N) ? cnt[node] : -1;
    const int tot = deg + 1;                  // self-inclusive; OOB -> 0
    sd[tid] = tot;
    for (int off = 1; off < 256; off <<= 1) {
        __syncthreads();
        int t = (tid >= off) ? sd[tid - off] : 0;
        __syncthreads();
        sd[tid] += t;
    }
    __syncthreads();
    if (tid == 255) sbase = atomicAdd(gcur, sd[255]);
    __syncthreads();
    const int rs = sbase + sd[tid] - tot;
    if (node < N) {
        rstart[node] = rs;
        cnt[node] = tot;
        dinv[node] = rsqrtf((float)tot);
        ssrc[rs] = node;                      // self entry (node index)
        cur[node] = rs + 1;
    }
}

__global__ __launch_bounds__(256) void k_fill(const int* __restrict__ ei,
                                              int* __restrict__ cur,
                                              int* __restrict__ ssrc, int E) {
    const int e = blockIdx.x * 256 + threadIdx.x;
    if (e < E) {
        const int s = __builtin_nontemporal_load(&ei[e]);
        const int d = __builtin_nontemporal_load(&ei[E + e]);
        const int pos = atomicAdd(&cur[d], 1);
        __builtin_nontemporal_store(s, &ssrc[pos]);
    }
}

// ---------------- element-wise prep ----------------

// xh = fp16(dinv ⊙ x): 4 elems per thread.
__global__ __launch_bounds__(256) void k_prescale(const float* __restrict__ x,
                                                  const float* __restrict__ dinv,
                                                  _Float16* __restrict__ xh, int N) {
    const int idx = blockIdx.x * 256 + threadIdx.x;   // over N*16
    if (idx >= N * 16) return;
    const int i = idx >> 4;
    const float dv = dinv[i];
    const floatx4 v = __builtin_nontemporal_load((const floatx4*)&x[(size_t)idx * 4]);
    half4v o;
    o[0] = (_Float16)(dv * v[0]); o[1] = (_Float16)(dv * v[1]);
    o[2] = (_Float16)(dv * v[2]); o[3] = (_Float16)(dv * v[3]);
    *(half4v*)(xh + (size_t)idx * 4) = o;   // temporal: gather1 wants it in L2
}

// Prep W1/W2 into MFMA B-fragment-ordered fp16 buffers.
__global__ __launch_bounds__(256) void k_prep(const float* __restrict__ W1,
                                              const float* __restrict__ W2,
                                              _Float16* __restrict__ w1f,
                                              _Float16* __restrict__ w2f) {
    const int idx = blockIdx.x * 256 + threadIdx.x;
    if (idx < 1024) {                       // W1: nt 0..7, kk 0..1, lane
        const int lane = idx & 63;
        const int kk = (idx >> 6) & 1;
        const int nt = idx >> 7;
        const int quad = lane >> 4, col = lane & 15;
        half8 o;
#pragma unroll
        for (int j = 0; j < 8; ++j) {
            const int k = kk * 32 + quad * 8 + j;
            const int n = nt * 16 + col;
            o[j] = (_Float16)W1[k * HID + n];
        }
        *(half8*)(w1f + (size_t)idx * 8) = o;
    } else if (idx < 1024 + 768) {          // W2: nt 0..2, kk 0..3, lane (n pad 48)
        const int i2 = idx - 1024;
        const int lane = i2 & 63;
        const int kk = (i2 >> 6) & 3;
        const int nt = i2 >> 8;
        const int quad = lane >> 4, col = lane & 15;
        half8 o;
#pragma unroll
        for (int j = 0; j < 8; ++j) {
            const int k = kk * 32 + quad * 8 + j;
            const int n = nt * 16 + col;
            o[j] = (n < CLS) ? (_Float16)W2[k * CLS + n] : (_Float16)0.f;
        }
        *(half8*)(w2f + (size_t)i2 * 8) = o;
    }
}

// ---------------- group-per-row packed fp16 gather ----------------
// X: fp16 rows of ROWB bytes, row N = zeros. Wave handles 8 rows: group g
// (8 lanes) owns row wave*8+g; lane owns a fixed 16B chunk; edges accumulate
// serially in-lane -> zero reduction. ssrc holds NODE indices; byte offset
// computed per gather (<<7 for 128B rows, *80 for compact 80B rows). For
// ROWB=80 subs 5..7 alias sub4's chunk (same cache line, lanes never write).

template <bool HALF_OUT, int FOUT, bool BIAS, int ROWB>
__global__ __launch_bounds__(256) void k_gather8(const _Float16* __restrict__ X,
                                                 const float* __restrict__ dinv,
                                                 const int* __restrict__ rstart,
                                                 const int* __restrict__ cnt,
                                                 const int* __restrict__ ssrc,
                                                 const float* __restrict__ bias,
                                                 void* __restrict__ outv,
                                                 int N) {
    const int wave = (blockIdx.x * 256 + threadIdx.x) >> 6;
    const int lane = threadIdx.x & 63;
    const int g = lane >> 3, sub = lane & 7;
    const int r = wave * 8 + g;
    const int rc = min(r, N - 1);
    const int st = rstart[rc];
    const int total = cnt[rc];             // self-inclusive, >= 1
    int maxtot = total;                    // wave-max iteration bound
    maxtot = max(maxtot, __shfl_xor(maxtot, 8));
    maxtot = max(maxtot, __shfl_xor(maxtot, 16));
    maxtot = max(maxtot, __shfl_xor(maxtot, 32));
    const char* Xb = (const char*)X;
    const int coff = (ROWB == 128) ? (sub << 4) : (min(sub, 4) << 4);
    half2v acc2[4] = {half2v{0, 0}, half2v{0, 0}, half2v{0, 0}, half2v{0, 0}};
    for (int base = 0; base < maxtot; base += 8) {
        const int idx = base + sub;
        int myN = __builtin_nontemporal_load(&ssrc[st + min(idx, total - 1)]);
        myN = (idx < total) ? myN : N;     // OOB -> zero row
        const int myO = (ROWB == 128) ? (myN << 7) : (myN * 80);
#pragma unroll
        for (int jj = 0; jj < 8; ++jj) {
            const int off = __shfl(myO, g * 8 + jj);
            const half8 hv = *(const half8*)(Xb + off + coff);
            const half2v* h2 = (const half2v*)&hv;
            acc2[0] += h2[0]; acc2[1] += h2[1];
            acc2[2] += h2[2]; acc2[3] += h2[3];
        }
    }
    if (r >= N) return;
    const float dv = dinv[r];
    float acc[8];
#pragma unroll
    for (int k = 0; k < 8; ++k) acc[k] = (float)acc2[k >> 1][k & 1] * dv;
    if (HALF_OUT) {
        half8 o;
#pragma unroll
        for (int k = 0; k < 8; ++k) o[k] = (_Float16)acc[k];
        __builtin_nontemporal_store(o, (half8*)((_Float16*)outv + ((size_t)r << 6) + (sub << 3)));
    } else {
        const int f0 = sub * 8;
        if (f0 < FOUT) {
            if (BIAS) {
                float4 bb0 = *(const float4*)&bias[f0];
                float4 bb1 = *(const float4*)&bias[f0 + 4];
                acc[0] += bb0.x; acc[1] += bb0.y; acc[2] += bb0.z; acc[3] += bb0.w;
                acc[4] += bb1.x; acc[5] += bb1.y; acc[6] += bb1.z; acc[7] += bb1.w;
            }
            float* op = (float*)outv + (size_t)r * FOUT + f0;
            const floatx4 o0 = {acc[0], acc[1], acc[2], acc[3]};
            const floatx4 o1 = {acc[4], acc[5], acc[6], acc[7]};
            __builtin_nontemporal_store(o0, (floatx4*)op);
            __builtin_nontemporal_store(o1, (floatx4*)(op + 4));
        }
    }
}

// ---------------- fused MFMA MLP: t -> h (regs) -> yh (80B rows) ----------------

__global__ __launch_bounds__(256, 3) void k_mlp(const _Float16* __restrict__ th,
                                                const _Float16* __restrict__ w1f,
                                                const float* __restrict__ b1,
                                                const _Float16* __restrict__ w2f,
                                                const float* __restrict__ dinv,
                                                _Float16* __restrict__ yh, int N) {
    __shared__ _Float16 hbuf[4][16 * 128];  // 16 KB
    const int tid = threadIdx.x;
    const int wave = tid >> 6, lane = tid & 63;
    const int quad = lane >> 4, col = lane & 15;
    const int row0 = blockIdx.x * 64 + wave * 16;
    const int arow = min(row0 + col, N - 1);
    const half8 a0 = __builtin_nontemporal_load((const half8*)(th + ((size_t)arow << 6) + quad * 8));
    const half8 a1 = __builtin_nontemporal_load((const half8*)(th + ((size_t)arow << 6) + 32 + quad * 8));
    floatx4 c[8];
#pragma unroll
    for (int nt = 0; nt < 8; ++nt) {
        c[nt] = (floatx4){0.f, 0.f, 0.f, 0.f};
        const half8 bb0 = *(const half8*)(w1f + (size_t)((nt * 2 + 0) * 64 + lane) * 8);
        const half8 bb1 = *(const half8*)(w1f + (size_t)((nt * 2 + 1) * 64 + lane) * 8);
        c[nt] = __builtin_amdgcn_mfma_f32_16x16x32_f16(a0, bb0, c[nt], 0, 0, 0);
        c[nt] = __builtin_amdgcn_mfma_f32_16x16x32_f16(a1, bb1, c[nt], 0, 0, 0);
    }
    _Float16* hb = hbuf[wave];
#pragma unroll
    for (int nt = 0; nt < 8; ++nt) {
        const float bv = b1[nt * 16 + col];
#pragma unroll
        for (int reg = 0; reg < 4; ++reg) {
            const int rr = quad * 4 + reg;
            const int hcol = nt * 16 + col;
            const int chunk = ((hcol >> 3) ^ rr) & 15;
            hb[rr * 128 + chunk * 8 + (hcol & 7)] =
                (_Float16)fmaxf(c[nt][reg] + bv, 0.f);
        }
    }
    __syncthreads();
    half8 a2[4];
#pragma unroll
    for (int kk = 0; kk < 4; ++kk) {
        const int chunk = ((kk * 4 + quad) ^ col) & 15;
        a2[kk] = *(const half8*)(hb + col * 128 + chunk * 8);
    }
    floatx4 c2[3];
#pragma unroll
    for (int nt = 0; nt < 3; ++nt) {
        c2[nt] = (floatx4){0.f, 0.f, 0.f, 0.f};
#pragma unroll
        for (int kk = 0; kk < 4; ++kk) {
            const half8 bb = *(const half8*)(w2f + (size_t)((nt * 4 + kk) * 64 + lane) * 8);
            c2[nt] = __builtin_amdgcn_mfma_f32_16x16x32_f16(a2[kk], bb, c2[nt], 0, 0, 0);
        }
    }
#pragma unroll
    for (int reg = 0; reg < 4; ++reg) {
        const int gr = row0 + quad * 4 + reg;
        const float dvr = dinv[min(gr, N - 1)];
#pragma unroll
        for (int nt = 0; nt < 3; ++nt) {
            const int cc = nt * 16 + col;
            if (gr < N && cc < CLS)
                yh[(size_t)gr * 40 + cc] = (_Float16)(c2[nt][reg] * dvr);
        }
    }
    // no pad writes: yh rows are exactly 40 halves (80B)
}

// ---------------- launch ----------------

extern "C" void kernel_launch(void* const* d_in, const int* in_sizes, int n_in,
                              void* d_out, int out_size, void* d_ws, size_t ws_size,
                              hipStream_t stream) {
    const float* x  = (const float*)d_in[0];
    const int*   ei = (const int*)d_in[1];   // [2][E]
    const float* W1 = (const float*)d_in[2];
    const float* b1 = (const float*)d_in[3];
    const float* W2 = (const float*)d_in[4];
    const float* b2 = (const float*)d_in[5];
    float* out = (float*)d_out;

    const int N = in_sizes[0] / FIN;
    const int E = in_sizes[1] / 2;

    char* p = (char*)d_ws;
    auto alloc = [&](size_t bytes) {
        char* q = p;
        p += (bytes + 255) & ~(size_t)255;   // keep every array 256B-aligned
        return q;
    };
    float* dinv    = (float*)alloc((size_t)N * 4);
    _Float16* th   = (_Float16*)alloc((size_t)(N + 1) * 128);  // 128B rows
    _Float16* xh   = (_Float16*)alloc((size_t)(N + 1) * 128);  // 128B rows
    _Float16* yh   = (_Float16*)alloc((size_t)(N + 1) * 80);   // 80B rows
    int* cnt       = (int*)alloc((size_t)N * 4);
    int* cur       = (int*)alloc((size_t)N * 4);
    int* rstart    = (int*)alloc((size_t)N * 4);
    int* ssrc      = (int*)alloc((size_t)(E + N) * 4);
    int* gcur      = (int*)alloc(4);
    _Float16* w1f  = (_Float16*)alloc(8192 * 2);
    _Float16* w2f  = (_Float16*)alloc(6144 * 2);

    dim3 blk(256);
    const int nbN = (N + 255) / 256;
    const int nbE = (E + 255) / 256;
    // weight prep (independent)
    hipLaunchKernelGGL(k_prep,  dim3(7), blk, 0, stream, W1, W2, w1f, w2f);
    // CSR build: zero -> degree -> allocate -> fill
    hipLaunchKernelGGL(kZ,      dim3(nbN), blk, 0, stream, cnt, gcur, xh, yh, N);
    hipLaunchKernelGGL(k_deg,   dim3(nbE), blk, 0, stream, ei + E, cnt, E);
    hipLaunchKernelGGL(k_alloc, dim3(nbN), blk, 0, stream, cnt, cur, rstart, dinv, ssrc, gcur, N);
    hipLaunchKernelGGL(k_fill,  dim3(nbE), blk, 0, stream, ei, cur, ssrc, E);
    // layer 1: prescale -> group-per-row gather (fp16 out, 128B rows)
    hipLaunchKernelGGL(k_prescale, dim3((N * 16 + 255) / 256), blk, 0, stream, x, dinv, xh, N);
    hipLaunchKernelGGL((k_gather8<true, FIN, false, 128>), dim3((N + 31) / 32), blk, 0, stream,
                       xh, dinv, rstart, cnt, ssrc, (const float*)nullptr, (void*)th, N);
    // fused MFMA MLP: t -> h -> yh (80B rows)
    hipLaunchKernelGGL(k_mlp, dim3((N + 63) / 64), blk, 0, stream, th, w1f, b1, w2f, dinv, yh, N);
    // layer 2 aggregate + bias -> out
    hipLaunchKernelGGL((k_gather8<false, CLS, true, 80>), dim3((N + 31) / 32), blk, 0, stream,
                       yh, dinv, rstart, cnt, ssrc, b2, (void*)out, N);
}

// Round 2
// 208.428 us; speedup vs baseline: 1.7660x; 1.7660x over previous
//
#include <hip/hip_runtime.h>
#include <hip/hip_bf16.h>

// GCN 2-layer forward on gfx950 — CSR radix partition, group-per-row packed
// fp16 gathers (no cross-lane reduction), fused fp16-MFMA MLP.
//
//   xh = fp16(dinv ⊙ x)            (row N = zeros, the OOB target; 128B rows)
//   t  = fp16( dinv[d] * Σ_{s∈csr[d]} xh[s] )     (gather, self-inclusive)
//   h  = relu(t W1 + b1)   [MFMA, C-frags in regs]
//   yh = fp16(dinv ⊙ (h W2))  — COMPACT 80B rows (40 halves, no pad)
//   out[d] = dinv[d] * Σ yh[s] + b2               (gather)
//
// R13: revert R12's direct-atomic CSR build (k_fill: 131us, WRITE_SIZE
// 107MB — globally-random 4B scatter + nt store = full-line eviction per
// edge). The radix partition's value is WRITE LOCALITY: each WG scatters
// into per-(bucket,WG) contiguous sub-ranges that coalesce in L2. Keep
// R12's verified-correct wins: ssrc stores node INDICES (gathers scale to
// row stride), yh compacted to 80B rows (k_mlp drops 4.8MB pad writes,
// gather2 footprint 12.8->8MB), nontemporal hints on streaming operands
// only (ssrc reads, th/out stores — never scattered dword stores).

static constexpr int FIN = 64;
static constexpr int HID = 128;
static constexpr int CLS = 40;
static constexpr int NB_MAX = 392;   // buckets of 256 nodes; N <= 100352
static constexpr int NWG_P = 256;    // partition workgroups

typedef _Float16 half8 __attribute__((ext_vector_type(8)));
typedef _Float16 half4v __attribute__((ext_vector_type(4)));
typedef _Float16 half2v __attribute__((ext_vector_type(2)));
typedef float floatx4 __attribute__((ext_vector_type(4)));

// ---------------- CSR build: radix partition by dst>>8 ----------------

__global__ __launch_bounds__(1024) void k_cnt(const int* __restrict__ dst,
                                              int* __restrict__ cntmat,
                                              int E, int NB, int per_wg) {
    __shared__ int lh[NB_MAX];
    const int tid = threadIdx.x, wg = blockIdx.x;
    for (int i = tid; i < NB; i += 1024) lh[i] = 0;
    __syncthreads();
    const int r0 = wg * per_wg, r1 = min(E, r0 + per_wg);
    for (int e = r0 + tid; e < r1; e += 1024)
        atomicAdd(&lh[dst[e] >> 8], 1);
    __syncthreads();
    for (int b = tid; b < NB; b += 1024) cntmat[b * NWG_P + wg] = lh[b];
}

__global__ __launch_bounds__(256) void k_bscan1(int* __restrict__ cntmat,
                                                int* __restrict__ btot) {
    __shared__ int sd[256];
    const int b = blockIdx.x, tid = threadIdx.x;
    int v = cntmat[b * NWG_P + tid];
    sd[tid] = v;
    for (int off = 1; off < 256; off <<= 1) {
        __syncthreads();
        int t = (tid >= off) ? sd[tid - off] : 0;
        __syncthreads();
        sd[tid] += t;
    }
    __syncthreads();
    cntmat[b * NWG_P + tid] = sd[tid] - v;
    if (tid == 255) btot[b] = sd[255];
}

__global__ __launch_bounds__(512) void k_bscan2(const int* __restrict__ btot,
                                                int* __restrict__ bbase,
                                                int NB, int E) {
    __shared__ int sd[512];
    const int tid = threadIdx.x;
    int v = (tid < NB) ? btot[tid] : 0;
    sd[tid] = v;
    for (int off = 1; off < 512; off <<= 1) {
        __syncthreads();
        int t = (tid >= off) ? sd[tid - off] : 0;
        __syncthreads();
        sd[tid] += t;
    }
    __syncthreads();
    if (tid < NB) bbase[tid] = sd[tid] - v;
    if (tid == 0) bbase[NB] = E;
}

__global__ __launch_bounds__(1024) void k_scat(const int* __restrict__ ei,
                                               const int* __restrict__ cntmat,
                                               const int* __restrict__ bbase,
                                               unsigned* __restrict__ tmp,
                                               int E, int NB, int per_wg) {
    __shared__ int lcur[NB_MAX];
    const int tid = threadIdx.x, wg = blockIdx.x;
    for (int b = tid; b < NB; b += 1024)
        lcur[b] = cntmat[b * NWG_P + wg] + bbase[b];
    __syncthreads();
    const int r0 = wg * per_wg, r1 = min(E, r0 + per_wg);
    for (int e = r0 + tid; e < r1; e += 1024) {
        int s = ei[e], d = ei[E + e];
        int b = d >> 8;
        int pos = atomicAdd(&lcur[b], 1);
        tmp[pos] = ((unsigned)(d & 255) << 24) | (unsigned)s;
    }
}

// P2: one WG per bucket. Self-inclusive adjacency; ssrc holds NODE indices.
__global__ __launch_bounds__(256) void k_p2(const unsigned* __restrict__ tmp,
                                            const int* __restrict__ bbase,
                                            int* __restrict__ rstart,
                                            int* __restrict__ cnt,
                                            float* __restrict__ dinv,
                                            int* __restrict__ ssrc, int N) {
    __shared__ int nh[256];
    __shared__ int sd[256];
    __shared__ int curs[256];
    const int tid = threadIdx.x;
    const int b = blockIdx.x;
    const int node0 = b << 8;
    const int e0 = bbase[b], e1 = bbase[b + 1];
    nh[tid] = 0;
    __syncthreads();
    for (int e = e0 + tid; e < e1; e += 256)
        atomicAdd(&nh[tmp[e] >> 24], 1);
    __syncthreads();
    int v = nh[tid];
    sd[tid] = v;
    for (int off = 1; off < 256; off <<= 1) {
        __syncthreads();
        int t = (tid >= off) ? sd[tid - off] : 0;
        __syncthreads();
        sd[tid] += t;
    }
    __syncthreads();
    int rs = e0 + node0 + (sd[tid] - v) + tid;
    int node = node0 + tid;
    if (node < N) {
        rstart[node] = rs;
        cnt[node] = v + 1;                 // self-inclusive
        dinv[node] = rsqrtf((float)v + 1.0f);
        ssrc[rs] = node;                   // self entry (node index)
    }
    curs[tid] = rs + 1;
    __syncthreads();
    for (int e = e0 + tid; e < e1; e += 256) {
        unsigned p = tmp[e];
        int slot = atomicAdd(&curs[p >> 24], 1);
        ssrc[slot] = (int)(p & 0xFFFFFFu);  // node index
    }
}

// ---------------- element-wise prep ----------------

// xh = fp16(dinv ⊙ x): 4 elems per thread.
__global__ __launch_bounds__(256) void k_prescale(const float* __restrict__ x,
                                                  const float* __restrict__ dinv,
                                                  _Float16* __restrict__ xh, int N) {
    const int idx = blockIdx.x * 256 + threadIdx.x;   // over N*16
    if (idx >= N * 16) return;
    const int i = idx >> 4;
    const float dv = dinv[i];
    const floatx4 v = __builtin_nontemporal_load((const floatx4*)&x[(size_t)idx * 4]);
    half4v o;
    o[0] = (_Float16)(dv * v[0]); o[1] = (_Float16)(dv * v[1]);
    o[2] = (_Float16)(dv * v[2]); o[3] = (_Float16)(dv * v[3]);
    *(half4v*)(xh + (size_t)idx * 4) = o;   // temporal: gather1 wants it in L2
}

// Zero the OOB target rows (index N) of xh and yh.
__global__ void k_zrows(_Float16* __restrict__ xh, _Float16* __restrict__ yh, int N) {
    const int t = threadIdx.x;
    if (t < 64) xh[(size_t)N * 64 + t] = (_Float16)0;
    if (t < 40) yh[(size_t)N * 40 + t] = (_Float16)0;
}

// Prep W1/W2 into MFMA B-fragment-ordered fp16 buffers.
__global__ __launch_bounds__(256) void k_prep(const float* __restrict__ W1,
                                              const float* __restrict__ W2,
                                              _Float16* __restrict__ w1f,
                                              _Float16* __restrict__ w2f) {
    const int idx = blockIdx.x * 256 + threadIdx.x;
    if (idx < 1024) {                       // W1: nt 0..7, kk 0..1, lane
        const int lane = idx & 63;
        const int kk = (idx >> 6) & 1;
        const int nt = idx >> 7;
        const int quad = lane >> 4, col = lane & 15;
        half8 o;
#pragma unroll
        for (int j = 0; j < 8; ++j) {
            const int k = kk * 32 + quad * 8 + j;
            const int n = nt * 16 + col;
            o[j] = (_Float16)W1[k * HID + n];
        }
        *(half8*)(w1f + (size_t)idx * 8) = o;
    } else if (idx < 1024 + 768) {          // W2: nt 0..2, kk 0..3, lane (n pad 48)
        const int i2 = idx - 1024;
        const int lane = i2 & 63;
        const int kk = (i2 >> 6) & 3;
        const int nt = i2 >> 8;
        const int quad = lane >> 4, col = lane & 15;
        half8 o;
#pragma unroll
        for (int j = 0; j < 8; ++j) {
            const int k = kk * 32 + quad * 8 + j;
            const int n = nt * 16 + col;
            o[j] = (n < CLS) ? (_Float16)W2[k * CLS + n] : (_Float16)0.f;
        }
        *(half8*)(w2f + (size_t)i2 * 8) = o;
    }
}

// ---------------- group-per-row packed fp16 gather ----------------
// X: fp16 rows of ROWB bytes, row N = zeros. Wave handles 8 rows: group g
// (8 lanes) owns row wave*8+g; lane owns a fixed 16B chunk; edges accumulate
// serially in-lane -> zero reduction. ssrc holds NODE indices; byte offset
// computed per gather (<<7 for 128B rows, *80 for compact 80B rows). For
// ROWB=80 subs 5..7 alias sub4's chunk (same cache line, lanes never write).

template <bool HALF_OUT, int FOUT, bool BIAS, int ROWB>
__global__ __launch_bounds__(256) void k_gather8(const _Float16* __restrict__ X,
                                                 const float* __restrict__ dinv,
                                                 const int* __restrict__ rstart,
                                                 const int* __restrict__ cnt,
                                                 const int* __restrict__ ssrc,
                                                 const float* __restrict__ bias,
                                                 void* __restrict__ outv,
                                                 int N) {
    const int wave = (blockIdx.x * 256 + threadIdx.x) >> 6;
    const int lane = threadIdx.x & 63;
    const int g = lane >> 3, sub = lane & 7;
    const int r = wave * 8 + g;
    const int rc = min(r, N - 1);
    const int st = rstart[rc];
    const int total = cnt[rc];             // self-inclusive, >= 1
    int maxtot = total;                    // wave-max iteration bound
    maxtot = max(maxtot, __shfl_xor(maxtot, 8));
    maxtot = max(maxtot, __shfl_xor(maxtot, 16));
    maxtot = max(maxtot, __shfl_xor(maxtot, 32));
    const char* Xb = (const char*)X;
    const int coff = (ROWB == 128) ? (sub << 4) : (min(sub, 4) << 4);
    half2v acc2[4] = {half2v{0, 0}, half2v{0, 0}, half2v{0, 0}, half2v{0, 0}};
    for (int base = 0; base < maxtot; base += 8) {
        const int idx = base + sub;
        int myN = __builtin_nontemporal_load(&ssrc[st + min(idx, total - 1)]);
        myN = (idx < total) ? myN : N;     // OOB -> zero row
        const int myO = (ROWB == 128) ? (myN << 7) : (myN * 80);
#pragma unroll
        for (int jj = 0; jj < 8; ++jj) {
            const int off = __shfl(myO, g * 8 + jj);
            const half8 hv = *(const half8*)(Xb + off + coff);
            const half2v* h2 = (const half2v*)&hv;
            acc2[0] += h2[0]; acc2[1] += h2[1];
            acc2[2] += h2[2]; acc2[3] += h2[3];
        }
    }
    if (r >= N) return;
    const float dv = dinv[r];
    float acc[8];
#pragma unroll
    for (int k = 0; k < 8; ++k) acc[k] = (float)acc2[k >> 1][k & 1] * dv;
    if (HALF_OUT) {
        half8 o;
#pragma unroll
        for (int k = 0; k < 8; ++k) o[k] = (_Float16)acc[k];
        __builtin_nontemporal_store(o, (half8*)((_Float16*)outv + ((size_t)r << 6) + (sub << 3)));
    } else {
        const int f0 = sub * 8;
        if (f0 < FOUT) {
            if (BIAS) {
                float4 bb0 = *(const float4*)&bias[f0];
                float4 bb1 = *(const float4*)&bias[f0 + 4];
                acc[0] += bb0.x; acc[1] += bb0.y; acc[2] += bb0.z; acc[3] += bb0.w;
                acc[4] += bb1.x; acc[5] += bb1.y; acc[6] += bb1.z; acc[7] += bb1.w;
            }
            float* op = (float*)outv + (size_t)r * FOUT + f0;
            const floatx4 o0 = {acc[0], acc[1], acc[2], acc[3]};
            const floatx4 o1 = {acc[4], acc[5], acc[6], acc[7]};
            __builtin_nontemporal_store(o0, (floatx4*)op);
            __builtin_nontemporal_store(o1, (floatx4*)(op + 4));
        }
    }
}

// ---------------- fused MFMA MLP: t -> h (regs) -> yh (80B rows) ----------------

__global__ __launch_bounds__(256, 3) void k_mlp(const _Float16* __restrict__ th,
                                                const _Float16* __restrict__ w1f,
                                                const float* __restrict__ b1,
                                                const _Float16* __restrict__ w2f,
                                                const float* __restrict__ dinv,
                                                _Float16* __restrict__ yh, int N) {
    __shared__ _Float16 hbuf[4][16 * 128];  // 16 KB
    const int tid = threadIdx.x;
    const int wave = tid >> 6, lane = tid & 63;
    const int quad = lane >> 4, col = lane & 15;
    const int row0 = blockIdx.x * 64 + wave * 16;
    const int arow = min(row0 + col, N - 1);
    const half8 a0 = __builtin_nontemporal_load((const half8*)(th + ((size_t)arow << 6) + quad * 8));
    const half8 a1 = __builtin_nontemporal_load((const half8*)(th + ((size_t)arow << 6) + 32 + quad * 8));
    floatx4 c[8];
#pragma unroll
    for (int nt = 0; nt < 8; ++nt) {
        c[nt] = (floatx4){0.f, 0.f, 0.f, 0.f};
        const half8 bb0 = *(const half8*)(w1f + (size_t)((nt * 2 + 0) * 64 + lane) * 8);
        const half8 bb1 = *(const half8*)(w1f + (size_t)((nt * 2 + 1) * 64 + lane) * 8);
        c[nt] = __builtin_amdgcn_mfma_f32_16x16x32_f16(a0, bb0, c[nt], 0, 0, 0);
        c[nt] = __builtin_amdgcn_mfma_f32_16x16x32_f16(a1, bb1, c[nt], 0, 0, 0);
    }
    _Float16* hb = hbuf[wave];
#pragma unroll
    for (int nt = 0; nt < 8; ++nt) {
        const float bv = b1[nt * 16 + col];
#pragma unroll
        for (int reg = 0; reg < 4; ++reg) {
            const int rr = quad * 4 + reg;
            const int hcol = nt * 16 + col;
            const int chunk = ((hcol >> 3) ^ rr) & 15;
            hb[rr * 128 + chunk * 8 + (hcol & 7)] =
                (_Float16)fmaxf(c[nt][reg] + bv, 0.f);
        }
    }
    __syncthreads();
    half8 a2[4];
#pragma unroll
    for (int kk = 0; kk < 4; ++kk) {
        const int chunk = ((kk * 4 + quad) ^ col) & 15;
        a2[kk] = *(const half8*)(hb + col * 128 + chunk * 8);
    }
    floatx4 c2[3];
#pragma unroll
    for (int nt = 0; nt < 3; ++nt) {
        c2[nt] = (floatx4){0.f, 0.f, 0.f, 0.f};
#pragma unroll
        for (int kk = 0; kk < 4; ++kk) {
            const half8 bb = *(const half8*)(w2f + (size_t)((nt * 4 + kk) * 64 + lane) * 8);
            c2[nt] = __builtin_amdgcn_mfma_f32_16x16x32_f16(a2[kk], bb, c2[nt], 0, 0, 0);
        }
    }
#pragma unroll
    for (int reg = 0; reg < 4; ++reg) {
        const int gr = row0 + quad * 4 + reg;
        const float dvr = dinv[min(gr, N - 1)];
#pragma unroll
        for (int nt = 0; nt < 3; ++nt) {
            const int cc = nt * 16 + col;
            if (gr < N && cc < CLS)
                yh[(size_t)gr * 40 + cc] = (_Float16)(c2[nt][reg] * dvr);
        }
    }
    // no pad writes: yh rows are exactly 40 halves (80B)
}

// ---------------- launch ----------------

extern "C" void kernel_launch(void* const* d_in, const int* in_sizes, int n_in,
                              void* d_out, int out_size, void* d_ws, size_t ws_size,
                              hipStream_t stream) {
    const float* x  = (const float*)d_in[0];
    const int*   ei = (const int*)d_in[1];   // [2][E]
    const float* W1 = (const float*)d_in[2];
    const float* b1 = (const float*)d_in[3];
    const float* W2 = (const float*)d_in[4];
    const float* b2 = (const float*)d_in[5];
    float* out = (float*)d_out;

    const int N = in_sizes[0] / FIN;
    const int E = in_sizes[1] / 2;
    const int NB = (N + 255) >> 8;
    const int per_wg = (E + NWG_P - 1) / NWG_P;

    char* p = (char*)d_ws;
    auto alloc = [&](size_t bytes) {
        char* q = p;
        p += (bytes + 255) & ~(size_t)255;   // keep every array 256B-aligned
        return q;
    };
    float* dinv    = (float*)alloc((size_t)N * 4);
    _Float16* th   = (_Float16*)alloc((size_t)(N + 1) * 128);  // 128B rows
    _Float16* xh   = (_Float16*)alloc((size_t)(N + 1) * 128);  // 128B rows
    _Float16* yh   = (_Float16*)alloc((size_t)(N + 1) * 80);   // 80B rows
    int* cnt       = (int*)alloc((size_t)N * 4);
    int* rstart    = (int*)alloc((size_t)N * 4);
    int* ssrc      = (int*)alloc((size_t)(E + N) * 4);
    int* cntmat    = (int*)alloc((size_t)NB_MAX * NWG_P * 4);
    int* btot      = (int*)alloc((size_t)NB_MAX * 4);
    int* bbase     = (int*)alloc((size_t)(NB_MAX + 1) * 4);
    unsigned* tmp  = (unsigned*)alloc((size_t)E * 4);
    _Float16* w1f  = (_Float16*)alloc(8192 * 2);
    _Float16* w2f  = (_Float16*)alloc(6144 * 2);

    dim3 blk(256);
    // CSR build (radix partition: write locality for the edge scatter)
    hipLaunchKernelGGL(k_cnt,    dim3(NWG_P), dim3(1024), 0, stream, ei + E, cntmat, E, NB, per_wg);
    hipLaunchKernelGGL(k_bscan1, dim3(NB), blk, 0, stream, cntmat, btot);
    hipLaunchKernelGGL(k_bscan2, dim3(1), dim3(512), 0, stream, btot, bbase, NB, E);
    hipLaunchKernelGGL(k_scat,   dim3(NWG_P), dim3(1024), 0, stream, ei, cntmat, bbase, tmp, E, NB, per_wg);
    hipLaunchKernelGGL(k_p2,     dim3(NB), blk, 0, stream, tmp, bbase, rstart, cnt, dinv, ssrc, N);
    // weight prep + zero rows
    hipLaunchKernelGGL(k_prep,  dim3(7), blk, 0, stream, W1, W2, w1f, w2f);
    hipLaunchKernelGGL(k_zrows, dim3(1), dim3(64), 0, stream, xh, yh, N);
    // layer 1: prescale -> group-per-row gather (fp16 out, 128B rows)
    hipLaunchKernelGGL(k_prescale, dim3((N * 16 + 255) / 256), blk, 0, stream, x, dinv, xh, N);
    hipLaunchKernelGGL((k_gather8<true, FIN, false, 128>), dim3((N + 31) / 32), blk, 0, stream,
                       xh, dinv, rstart, cnt, ssrc, (const float*)nullptr, (void*)th, N);
    // fused MFMA MLP: t -> h -> yh (80B rows)
    hipLaunchKernelGGL(k_mlp, dim3((N + 63) / 64), blk, 0, stream, th, w1f, b1, w2f, dinv, yh, N);
    // layer 2 aggregate + bias -> out
    hipLaunchKernelGGL((k_gather8<false, CLS, true, 80>), dim3((N + 31) / 32), blk, 0, stream,
                       yh, dinv, rstart, cnt, ssrc, b2, (void*)out, N);
}

// Round 3
// 200.490 us; speedup vs baseline: 1.8360x; 1.0396x over previous
//
#include <hip/hip_runtime.h>
#include <hip/hip_bf16.h>

// GCN 2-layer forward on gfx950 — CSR radix partition, group-per-row packed
// fp16 gathers (no cross-lane reduction), fused fp16-MFMA MLP.
//
//   xh = fp16(dinv ⊙ x)            (row N = zeros, the OOB target; 128B rows)
//   t  = fp16( dinv[d] * Σ_{s∈csr[d]} xh[s] )     (gather, self-inclusive)
//   h  = relu(t W1 + b1)   [MFMA, C-frags in regs]
//   yh = fp16(dinv ⊙ (h W2)) padded to 64 cols (128B rows, cols 40..63 = 0)
//   out[d] = dinv[d] * Σ yh[s] + b2               (gather)
//
// R14: restore R11 geometry. R13's 80B yh rows straddled 64B sectors
// (avg ~2.25 sectors/touch vs 2 aligned) — footprint shrank but per-touch
// fetch grew; net +8.7us. Rows stay 128B-aligned: random-gather fetch
// granularity beats footprint. Keep from R12/R13 only: ssrc = node
// indices (<<7 in gather), nontemporal on SINGLE-USE streams only
// (x load, th load in mlp, out store — never on data re-read later:
// ssrc, th store, yh store), and k_zrows folded into k_prep (10 launches).

static constexpr int FIN = 64;
static constexpr int HID = 128;
static constexpr int CLS = 40;
static constexpr int NB_MAX = 392;   // buckets of 256 nodes; N <= 100352
static constexpr int NWG_P = 256;    // partition workgroups

typedef _Float16 half8 __attribute__((ext_vector_type(8)));
typedef _Float16 half4v __attribute__((ext_vector_type(4)));
typedef _Float16 half2v __attribute__((ext_vector_type(2)));
typedef float floatx4 __attribute__((ext_vector_type(4)));

// ---------------- CSR build: radix partition by dst>>8 ----------------

__global__ __launch_bounds__(1024) void k_cnt(const int* __restrict__ dst,
                                              int* __restrict__ cntmat,
                                              int E, int NB, int per_wg) {
    __shared__ int lh[NB_MAX];
    const int tid = threadIdx.x, wg = blockIdx.x;
    for (int i = tid; i < NB; i += 1024) lh[i] = 0;
    __syncthreads();
    const int r0 = wg * per_wg, r1 = min(E, r0 + per_wg);
    for (int e = r0 + tid; e < r1; e += 1024)
        atomicAdd(&lh[dst[e] >> 8], 1);
    __syncthreads();
    for (int b = tid; b < NB; b += 1024) cntmat[b * NWG_P + wg] = lh[b];
}

__global__ __launch_bounds__(256) void k_bscan1(int* __restrict__ cntmat,
                                                int* __restrict__ btot) {
    __shared__ int sd[256];
    const int b = blockIdx.x, tid = threadIdx.x;
    int v = cntmat[b * NWG_P + tid];
    sd[tid] = v;
    for (int off = 1; off < 256; off <<= 1) {
        __syncthreads();
        int t = (tid >= off) ? sd[tid - off] : 0;
        __syncthreads();
        sd[tid] += t;
    }
    __syncthreads();
    cntmat[b * NWG_P + tid] = sd[tid] - v;
    if (tid == 255) btot[b] = sd[255];
}

__global__ __launch_bounds__(512) void k_bscan2(const int* __restrict__ btot,
                                                int* __restrict__ bbase,
                                                int NB, int E) {
    __shared__ int sd[512];
    const int tid = threadIdx.x;
    int v = (tid < NB) ? btot[tid] : 0;
    sd[tid] = v;
    for (int off = 1; off < 512; off <<= 1) {
        __syncthreads();
        int t = (tid >= off) ? sd[tid - off] : 0;
        __syncthreads();
        sd[tid] += t;
    }
    __syncthreads();
    if (tid < NB) bbase[tid] = sd[tid] - v;
    if (tid == 0) bbase[NB] = E;
}

__global__ __launch_bounds__(1024) void k_scat(const int* __restrict__ ei,
                                               const int* __restrict__ cntmat,
                                               const int* __restrict__ bbase,
                                               unsigned* __restrict__ tmp,
                                               int E, int NB, int per_wg) {
    __shared__ int lcur[NB_MAX];
    const int tid = threadIdx.x, wg = blockIdx.x;
    for (int b = tid; b < NB; b += 1024)
        lcur[b] = cntmat[b * NWG_P + wg] + bbase[b];
    __syncthreads();
    const int r0 = wg * per_wg, r1 = min(E, r0 + per_wg);
    for (int e = r0 + tid; e < r1; e += 1024) {
        int s = ei[e], d = ei[E + e];
        int b = d >> 8;
        int pos = atomicAdd(&lcur[b], 1);
        tmp[pos] = ((unsigned)(d & 255) << 24) | (unsigned)s;
    }
}

// P2: one WG per bucket. Self-inclusive adjacency; ssrc holds NODE indices.
__global__ __launch_bounds__(256) void k_p2(const unsigned* __restrict__ tmp,
                                            const int* __restrict__ bbase,
                                            int* __restrict__ rstart,
                                            int* __restrict__ cnt,
                                            float* __restrict__ dinv,
                                            int* __restrict__ ssrc, int N) {
    __shared__ int nh[256];
    __shared__ int sd[256];
    __shared__ int curs[256];
    const int tid = threadIdx.x;
    const int b = blockIdx.x;
    const int node0 = b << 8;
    const int e0 = bbase[b], e1 = bbase[b + 1];
    nh[tid] = 0;
    __syncthreads();
    for (int e = e0 + tid; e < e1; e += 256)
        atomicAdd(&nh[tmp[e] >> 24], 1);
    __syncthreads();
    int v = nh[tid];
    sd[tid] = v;
    for (int off = 1; off < 256; off <<= 1) {
        __syncthreads();
        int t = (tid >= off) ? sd[tid - off] : 0;
        __syncthreads();
        sd[tid] += t;
    }
    __syncthreads();
    int rs = e0 + node0 + (sd[tid] - v) + tid;
    int node = node0 + tid;
    if (node < N) {
        rstart[node] = rs;
        cnt[node] = v + 1;                 // self-inclusive
        dinv[node] = rsqrtf((float)v + 1.0f);
        ssrc[rs] = node;                   // self entry (node index)
    }
    curs[tid] = rs + 1;
    __syncthreads();
    for (int e = e0 + tid; e < e1; e += 256) {
        unsigned p = tmp[e];
        int slot = atomicAdd(&curs[p >> 24], 1);
        ssrc[slot] = (int)(p & 0xFFFFFFu);  // node index
    }
}

// ---------------- element-wise prep ----------------

// xh = fp16(dinv ⊙ x): 4 elems per thread. x is read-once -> nontemporal.
__global__ __launch_bounds__(256) void k_prescale(const float* __restrict__ x,
                                                  const float* __restrict__ dinv,
                                                  _Float16* __restrict__ xh, int N) {
    const int idx = blockIdx.x * 256 + threadIdx.x;   // over N*16
    if (idx >= N * 16) return;
    const int i = idx >> 4;
    const float dv = dinv[i];
    const floatx4 v = __builtin_nontemporal_load((const floatx4*)&x[(size_t)idx * 4]);
    half4v o;
    o[0] = (_Float16)(dv * v[0]); o[1] = (_Float16)(dv * v[1]);
    o[2] = (_Float16)(dv * v[2]); o[3] = (_Float16)(dv * v[3]);
    *(half4v*)(xh + (size_t)idx * 4) = o;   // temporal: gather1 wants it in L2
}

// Prep W1/W2 into MFMA B-fragment-ordered fp16 buffers; block 7 zeroes the
// OOB target rows (index N) of xh and yh (both 128B rows).
__global__ __launch_bounds__(256) void k_prep(const float* __restrict__ W1,
                                              const float* __restrict__ W2,
                                              _Float16* __restrict__ w1f,
                                              _Float16* __restrict__ w2f,
                                              _Float16* __restrict__ xh,
                                              _Float16* __restrict__ yh, int N) {
    const int idx = blockIdx.x * 256 + threadIdx.x;
    if (idx < 1024) {                       // W1: nt 0..7, kk 0..1, lane
        const int lane = idx & 63;
        const int kk = (idx >> 6) & 1;
        const int nt = idx >> 7;
        const int quad = lane >> 4, col = lane & 15;
        half8 o;
#pragma unroll
        for (int j = 0; j < 8; ++j) {
            const int k = kk * 32 + quad * 8 + j;
            const int n = nt * 16 + col;
            o[j] = (_Float16)W1[k * HID + n];
        }
        *(half8*)(w1f + (size_t)idx * 8) = o;
    } else if (idx < 1024 + 768) {          // W2: nt 0..2, kk 0..3, lane (n pad 48)
        const int i2 = idx - 1024;
        const int lane = i2 & 63;
        const int kk = (i2 >> 6) & 3;
        const int nt = i2 >> 8;
        const int quad = lane >> 4, col = lane & 15;
        half8 o;
#pragma unroll
        for (int j = 0; j < 8; ++j) {
            const int k = kk * 32 + quad * 8 + j;
            const int n = nt * 16 + col;
            o[j] = (n < CLS) ? (_Float16)W2[k * CLS + n] : (_Float16)0.f;
        }
        *(half8*)(w2f + (size_t)i2 * 8) = o;
    } else {                                // zero OOB rows
        const int t = idx - 1792;
        if (t < 64) {
            xh[(size_t)N * 64 + t] = (_Float16)0;
            yh[(size_t)N * 64 + t] = (_Float16)0;
        }
    }
}

// ---------------- group-per-row packed fp16 gather ----------------
// X: fp16 rows of 128B, row N = zeros. Wave handles 8 rows: group g (8
// lanes) owns row wave*8+g; lane owns a fixed 16B chunk; edges accumulate
// serially in-lane -> zero reduction. ssrc holds NODE indices (<<7 = byte
// offset). OOB slots broadcast the zero row N.

template <bool HALF_OUT, int FOUT, bool BIAS>
__global__ __launch_bounds__(256) void k_gather8(const _Float16* __restrict__ X,
                                                 const float* __restrict__ dinv,
                                                 const int* __restrict__ rstart,
                                                 const int* __restrict__ cnt,
                                                 const int* __restrict__ ssrc,
                                                 const float* __restrict__ bias,
                                                 void* __restrict__ outv,
                                                 int N) {
    const int wave = (blockIdx.x * 256 + threadIdx.x) >> 6;
    const int lane = threadIdx.x & 63;
    const int g = lane >> 3, sub = lane & 7;
    const int r = wave * 8 + g;
    const int rc = min(r, N - 1);
    const int st = rstart[rc];
    const int total = cnt[rc];             // self-inclusive, >= 1
    int maxtot = total;                    // wave-max iteration bound
    maxtot = max(maxtot, __shfl_xor(maxtot, 8));
    maxtot = max(maxtot, __shfl_xor(maxtot, 16));
    maxtot = max(maxtot, __shfl_xor(maxtot, 32));
    const char* Xb = (const char*)X;
    half2v acc2[4] = {half2v{0, 0}, half2v{0, 0}, half2v{0, 0}, half2v{0, 0}};
    for (int base = 0; base < maxtot; base += 8) {
        const int idx = base + sub;
        int myN = ssrc[st + min(idx, total - 1)];
        myN = (idx < total) ? myN : N;     // OOB -> zero row
        const int myO = myN << 7;          // 128B rows
#pragma unroll
        for (int jj = 0; jj < 8; ++jj) {
            const int off = __shfl(myO, g * 8 + jj);
            const half8 hv = *(const half8*)(Xb + off + (sub << 4));
            const half2v* h2 = (const half2v*)&hv;
            acc2[0] += h2[0]; acc2[1] += h2[1];
            acc2[2] += h2[2]; acc2[3] += h2[3];
        }
    }
    if (r >= N) return;
    const float dv = dinv[r];
    float acc[8];
#pragma unroll
    for (int k = 0; k < 8; ++k) acc[k] = (float)acc2[k >> 1][k & 1] * dv;
    if (HALF_OUT) {
        half8 o;
#pragma unroll
        for (int k = 0; k < 8; ++k) o[k] = (_Float16)acc[k];
        *(half8*)((_Float16*)outv + ((size_t)r << 6) + (sub << 3)) = o;  // re-read by mlp: temporal
    } else {
        const int f0 = sub * 8;
        if (f0 < FOUT) {
            if (BIAS) {
                float4 bb0 = *(const float4*)&bias[f0];
                float4 bb1 = *(const float4*)&bias[f0 + 4];
                acc[0] += bb0.x; acc[1] += bb0.y; acc[2] += bb0.z; acc[3] += bb0.w;
                acc[4] += bb1.x; acc[5] += bb1.y; acc[6] += bb1.z; acc[7] += bb1.w;
            }
            float* op = (float*)outv + (size_t)r * FOUT + f0;
            const floatx4 o0 = {acc[0], acc[1], acc[2], acc[3]};
            const floatx4 o1 = {acc[4], acc[5], acc[6], acc[7]};
            __builtin_nontemporal_store(o0, (floatx4*)op);      // out: write-once
            __builtin_nontemporal_store(o1, (floatx4*)(op + 4));
        }
    }
}

// ---------------- fused MFMA MLP: t -> h (regs) -> yh (128B rows) ----------------

__global__ __launch_bounds__(256, 3) void k_mlp(const _Float16* __restrict__ th,
                                                const _Float16* __restrict__ w1f,
                                                const float* __restrict__ b1,
                                                const _Float16* __restrict__ w2f,
                                                const float* __restrict__ dinv,
                                                _Float16* __restrict__ yh, int N) {
    __shared__ _Float16 hbuf[4][16 * 128];  // 16 KB
    const int tid = threadIdx.x;
    const int wave = tid >> 6, lane = tid & 63;
    const int quad = lane >> 4, col = lane & 15;
    const int row0 = blockIdx.x * 64 + wave * 16;
    const int arow = min(row0 + col, N - 1);
    // th is dead after this kernel -> nontemporal (frees L2 for yh/ssrc)
    const half8 a0 = __builtin_nontemporal_load((const half8*)(th + ((size_t)arow << 6) + quad * 8));
    const half8 a1 = __builtin_nontemporal_load((const half8*)(th + ((size_t)arow << 6) + 32 + quad * 8));
    floatx4 c[8];
#pragma unroll
    for (int nt = 0; nt < 8; ++nt) {
        c[nt] = (floatx4){0.f, 0.f, 0.f, 0.f};
        const half8 bb0 = *(const half8*)(w1f + (size_t)((nt * 2 + 0) * 64 + lane) * 8);
        const half8 bb1 = *(const half8*)(w1f + (size_t)((nt * 2 + 1) * 64 + lane) * 8);
        c[nt] = __builtin_amdgcn_mfma_f32_16x16x32_f16(a0, bb0, c[nt], 0, 0, 0);
        c[nt] = __builtin_amdgcn_mfma_f32_16x16x32_f16(a1, bb1, c[nt], 0, 0, 0);
    }
    _Float16* hb = hbuf[wave];
#pragma unroll
    for (int nt = 0; nt < 8; ++nt) {
        const float bv = b1[nt * 16 + col];
#pragma unroll
        for (int reg = 0; reg < 4; ++reg) {
            const int rr = quad * 4 + reg;
            const int hcol = nt * 16 + col;
            const int chunk = ((hcol >> 3) ^ rr) & 15;
            hb[rr * 128 + chunk * 8 + (hcol & 7)] =
                (_Float16)fmaxf(c[nt][reg] + bv, 0.f);
        }
    }
    __syncthreads();
    half8 a2[4];
#pragma unroll
    for (int kk = 0; kk < 4; ++kk) {
        const int chunk = ((kk * 4 + quad) ^ col) & 15;
        a2[kk] = *(const half8*)(hb + col * 128 + chunk * 8);
    }
    floatx4 c2[3];
#pragma unroll
    for (int nt = 0; nt < 3; ++nt) {
        c2[nt] = (floatx4){0.f, 0.f, 0.f, 0.f};
#pragma unroll
        for (int kk = 0; kk < 4; ++kk) {
            const half8 bb = *(const half8*)(w2f + (size_t)((nt * 4 + kk) * 64 + lane) * 8);
            c2[nt] = __builtin_amdgcn_mfma_f32_16x16x32_f16(a2[kk], bb, c2[nt], 0, 0, 0);
        }
    }
#pragma unroll
    for (int reg = 0; reg < 4; ++reg) {
        const int gr = row0 + quad * 4 + reg;
        const float dvr = dinv[min(gr, N - 1)];
#pragma unroll
        for (int nt = 0; nt < 3; ++nt) {
            const int cc = nt * 16 + col;
            if (gr < N && cc < CLS)
                yh[((size_t)gr << 6) + cc] = (_Float16)(c2[nt][reg] * dvr);
        }
    }
    // zero pad cols 40..63 (12 dwords per row)
    for (int i = lane; i < 16 * 12; i += 64) {
        const int row = row0 + i / 12;
        if (row < N)
            ((unsigned*)(yh + ((size_t)row << 6)))[20 + i % 12] = 0u;
    }
}

// ---------------- launch ----------------

extern "C" void kernel_launch(void* const* d_in, const int* in_sizes, int n_in,
                              void* d_out, int out_size, void* d_ws, size_t ws_size,
                              hipStream_t stream) {
    const float* x  = (const float*)d_in[0];
    const int*   ei = (const int*)d_in[1];   // [2][E]
    const float* W1 = (const float*)d_in[2];
    const float* b1 = (const float*)d_in[3];
    const float* W2 = (const float*)d_in[4];
    const float* b2 = (const float*)d_in[5];
    float* out = (float*)d_out;

    const int N = in_sizes[0] / FIN;
    const int E = in_sizes[1] / 2;
    const int NB = (N + 255) >> 8;
    const int per_wg = (E + NWG_P - 1) / NWG_P;

    char* p = (char*)d_ws;
    auto alloc = [&](size_t bytes) {
        char* q = p;
        p += (bytes + 255) & ~(size_t)255;   // keep every array 256B-aligned
        return q;
    };
    float* dinv    = (float*)alloc((size_t)N * 4);
    _Float16* th   = (_Float16*)alloc((size_t)(N + 1) * 128);  // 128B rows
    _Float16* xh   = (_Float16*)alloc((size_t)(N + 1) * 128);  // 128B rows
    _Float16* yh   = (_Float16*)alloc((size_t)(N + 1) * 128);  // 128B rows
    int* cnt       = (int*)alloc((size_t)N * 4);
    int* rstart    = (int*)alloc((size_t)N * 4);
    int* ssrc      = (int*)alloc((size_t)(E + N) * 4);
    int* cntmat    = (int*)alloc((size_t)NB_MAX * NWG_P * 4);
    int* btot      = (int*)alloc((size_t)NB_MAX * 4);
    int* bbase     = (int*)alloc((size_t)(NB_MAX + 1) * 4);
    unsigned* tmp  = (unsigned*)alloc((size_t)E * 4);
    _Float16* w1f  = (_Float16*)alloc(8192 * 2);
    _Float16* w2f  = (_Float16*)alloc(6144 * 2);

    dim3 blk(256);
    // weight prep + OOB zero rows (independent of everything else)
    hipLaunchKernelGGL(k_prep,  dim3(8), blk, 0, stream, W1, W2, w1f, w2f, xh, yh, N);
    // CSR build (radix partition: write locality for the edge scatter)
    hipLaunchKernelGGL(k_cnt,    dim3(NWG_P), dim3(1024), 0, stream, ei + E, cntmat, E, NB, per_wg);
    hipLaunchKernelGGL(k_bscan1, dim3(NB), blk, 0, stream, cntmat, btot);
    hipLaunchKernelGGL(k_bscan2, dim3(1), dim3(512), 0, stream, btot, bbase, NB, E);
    hipLaunchKernelGGL(k_scat,   dim3(NWG_P), dim3(1024), 0, stream, ei, cntmat, bbase, tmp, E, NB, per_wg);
    hipLaunchKernelGGL(k_p2,     dim3(NB), blk, 0, stream, tmp, bbase, rstart, cnt, dinv, ssrc, N);
    // layer 1: prescale -> group-per-row gather (fp16 out, 128B rows)
    hipLaunchKernelGGL(k_prescale, dim3((N * 16 + 255) / 256), blk, 0, stream, x, dinv, xh, N);
    hipLaunchKernelGGL((k_gather8<true, FIN, false>), dim3((N + 31) / 32), blk, 0, stream,
                       xh, dinv, rstart, cnt, ssrc, (const float*)nullptr, (void*)th, N);
    // fused MFMA MLP: t -> h -> yh (128B rows, cols 40..63 zeroed)
    hipLaunchKernelGGL(k_mlp, dim3((N + 63) / 64), blk, 0, stream, th, w1f, b1, w2f, dinv, yh, N);
    // layer 2 aggregate + bias -> out
    hipLaunchKernelGGL((k_gather8<false, CLS, true>), dim3((N + 31) / 32), blk, 0, stream,
                       yh, dinv, rstart, cnt, ssrc, b2, (void*)out, N);
}

// Round 4
// 195.847 us; speedup vs baseline: 1.8795x; 1.0237x over previous
//
#include <hip/hip_runtime.h>
#include <hip/hip_bf16.h>

// GCN 2-layer forward on gfx950 — CSR radix partition, group-per-row packed
// fp16 gathers (no cross-lane reduction), fused fp16-MFMA MLP.
//
//   xh = fp16(dinv ⊙ x)            (row N = zeros, the OOB target; 128B rows)
//   t  = fp16( dinv[d] * Σ_{s∈csr[d]} xh[s] )     (gather, self-inclusive)
//   h  = relu(t W1 + b1)   [MFMA, C-frags in regs]
//   yh = fp16(dinv ⊙ (h W2)) padded to 64 cols (128B rows, cols 40..63 = 0)
//   out[d] = dinv[d] * Σ yh[s] + b2               (gather)
//
// R15 (on R14 = baseline-equivalent):
//  (1) gather loop bound is now PER-GROUP (was wave-max): all 8 lanes of a
//      group share `total`, and __shfl only reads same-group lanes, so the
//      loop may diverge per group — exec-masking kills the ~20-30% zero-row
//      dummy loads the wave-max bound issued. Saves VMEM issue, not fetch.
//  (2) k_bscan2 eliminated: bucket regions need not be in memory order.
//      k_balloc atomically allocates region [bbase[b], bbase[b]+btot[b]+256)
//      per bucket off a global cursor (256 self slots included). p2 uses
//      e1 = bbase[b]+btot[b]; rs = e0 + prefix + tid. Regions disjoint.
//  (3) k_prep/k_zrows/gcur-init folded into k_cnt as 2 extra blocks.
//  10 -> 8 launches.

static constexpr int FIN = 64;
static constexpr int HID = 128;
static constexpr int CLS = 40;
static constexpr int NB_MAX = 392;   // buckets of 256 nodes; N <= 100352
static constexpr int NWG_P = 256;    // partition workgroups

typedef _Float16 half8 __attribute__((ext_vector_type(8)));
typedef _Float16 half4v __attribute__((ext_vector_type(4)));
typedef _Float16 half2v __attribute__((ext_vector_type(2)));
typedef float floatx4 __attribute__((ext_vector_type(4)));

// ---------------- CSR build: radix partition by dst>>8 ----------------

// Blocks 0..NWG_P-1: per-WG bucket histogram of dst.
// Blocks NWG_P..NWG_P+1: weight prep + OOB zero rows + gcur=0 (independent).
__global__ __launch_bounds__(1024) void k_cnt(const int* __restrict__ dst,
                                              int* __restrict__ cntmat,
                                              int E, int NB, int per_wg,
                                              const float* __restrict__ W1,
                                              const float* __restrict__ W2,
                                              _Float16* __restrict__ w1f,
                                              _Float16* __restrict__ w2f,
                                              _Float16* __restrict__ xh,
                                              _Float16* __restrict__ yh,
                                              int* __restrict__ gcur, int N) {
    __shared__ int lh[NB_MAX];
    const int tid = threadIdx.x, wg = blockIdx.x;
    if (wg < NWG_P) {
        for (int i = tid; i < NB; i += 1024) lh[i] = 0;
        __syncthreads();
        const int r0 = wg * per_wg, r1 = min(E, r0 + per_wg);
        for (int e = r0 + tid; e < r1; e += 1024)
            atomicAdd(&lh[dst[e] >> 8], 1);
        __syncthreads();
        for (int b = tid; b < NB; b += 1024) cntmat[b * NWG_P + wg] = lh[b];
        return;
    }
    // ---- prep blocks ----
    const int idx = (wg - NWG_P) * 1024 + tid;   // 0..2047
    if (idx < 1024) {                       // W1: nt 0..7, kk 0..1, lane
        const int lane = idx & 63;
        const int kk = (idx >> 6) & 1;
        const int nt = idx >> 7;
        const int quad = lane >> 4, col = lane & 15;
        half8 o;
#pragma unroll
        for (int j = 0; j < 8; ++j) {
            const int k = kk * 32 + quad * 8 + j;
            const int n = nt * 16 + col;
            o[j] = (_Float16)W1[k * HID + n];
        }
        *(half8*)(w1f + (size_t)idx * 8) = o;
    } else if (idx < 1024 + 768) {          // W2: nt 0..2, kk 0..3, lane (n pad 48)
        const int i2 = idx - 1024;
        const int lane = i2 & 63;
        const int kk = (i2 >> 6) & 3;
        const int nt = i2 >> 8;
        const int quad = lane >> 4, col = lane & 15;
        half8 o;
#pragma unroll
        for (int j = 0; j < 8; ++j) {
            const int k = kk * 32 + quad * 8 + j;
            const int n = nt * 16 + col;
            o[j] = (n < CLS) ? (_Float16)W2[k * CLS + n] : (_Float16)0.f;
        }
        *(half8*)(w2f + (size_t)i2 * 8) = o;
    } else if (idx < 1792 + 64) {           // zero OOB rows (index N)
        const int t = idx - 1792;
        xh[(size_t)N * 64 + t] = (_Float16)0;
        yh[(size_t)N * 64 + t] = (_Float16)0;
    } else if (idx == 1792 + 64) {
        *gcur = 0;
    }
}

// Per-bucket scan of cntmat row + ATOMIC region allocation (order-free):
// region [bbase[b], bbase[b] + btot[b] + 256) holds this bucket's tmp edges
// (first btot[b]) and ssrc entries (self + edges, interleaved by p2).
__global__ __launch_bounds__(256) void k_balloc(int* __restrict__ cntmat,
                                                int* __restrict__ bbase,
                                                int* __restrict__ btot,
                                                int* __restrict__ gcur) {
    __shared__ int sd[256];
    const int b = blockIdx.x, tid = threadIdx.x;
    int v = cntmat[b * NWG_P + tid];
    sd[tid] = v;
    for (int off = 1; off < 256; off <<= 1) {
        __syncthreads();
        int t = (tid >= off) ? sd[tid - off] : 0;
        __syncthreads();
        sd[tid] += t;
    }
    __syncthreads();
    cntmat[b * NWG_P + tid] = sd[tid] - v;
    if (tid == 255) {
        const int tot = sd[255];
        btot[b] = tot;
        bbase[b] = atomicAdd(gcur, tot + 256);
    }
}

__global__ __launch_bounds__(1024) void k_scat(const int* __restrict__ ei,
                                               const int* __restrict__ cntmat,
                                               const int* __restrict__ bbase,
                                               unsigned* __restrict__ tmp,
                                               int E, int NB, int per_wg) {
    __shared__ int lcur[NB_MAX];
    const int tid = threadIdx.x, wg = blockIdx.x;
    for (int b = tid; b < NB; b += 1024)
        lcur[b] = cntmat[b * NWG_P + wg] + bbase[b];
    __syncthreads();
    const int r0 = wg * per_wg, r1 = min(E, r0 + per_wg);
    for (int e = r0 + tid; e < r1; e += 1024) {
        int s = ei[e], d = ei[E + e];
        int b = d >> 8;
        int pos = atomicAdd(&lcur[b], 1);
        tmp[pos] = ((unsigned)(d & 255) << 24) | (unsigned)s;
    }
}

// P2: one WG per bucket. Self-inclusive adjacency; ssrc holds NODE indices.
// Bucket b's edges: tmp[e0 .. e0+btot[b]), region for ssrc entries:
// [e0, e0 + btot[b] + 256).
__global__ __launch_bounds__(256) void k_p2(const unsigned* __restrict__ tmp,
                                            const int* __restrict__ bbase,
                                            const int* __restrict__ btot,
                                            int* __restrict__ rstart,
                                            int* __restrict__ cnt,
                                            float* __restrict__ dinv,
                                            int* __restrict__ ssrc, int N) {
    __shared__ int nh[256];
    __shared__ int sd[256];
    __shared__ int curs[256];
    const int tid = threadIdx.x;
    const int b = blockIdx.x;
    const int node0 = b << 8;
    const int e0 = bbase[b], e1 = e0 + btot[b];
    nh[tid] = 0;
    __syncthreads();
    for (int e = e0 + tid; e < e1; e += 256)
        atomicAdd(&nh[tmp[e] >> 24], 1);
    __syncthreads();
    int v = nh[tid];
    sd[tid] = v;
    for (int off = 1; off < 256; off <<= 1) {
        __syncthreads();
        int t = (tid >= off) ? sd[tid - off] : 0;
        __syncthreads();
        sd[tid] += t;
    }
    __syncthreads();
    int rs = e0 + (sd[tid] - v) + tid;     // self + edges, within region
    int node = node0 + tid;
    if (node < N) {
        rstart[node] = rs;
        cnt[node] = v + 1;                 // self-inclusive
        dinv[node] = rsqrtf((float)v + 1.0f);
        ssrc[rs] = node;                   // self entry (node index)
    }
    curs[tid] = rs + 1;
    __syncthreads();
    for (int e = e0 + tid; e < e1; e += 256) {
        unsigned p = tmp[e];
        int slot = atomicAdd(&curs[p >> 24], 1);
        ssrc[slot] = (int)(p & 0xFFFFFFu);  // node index
    }
}

// ---------------- element-wise prep ----------------

// xh = fp16(dinv ⊙ x): 4 elems per thread. x is read-once -> nontemporal.
__global__ __launch_bounds__(256) void k_prescale(const float* __restrict__ x,
                                                  const float* __restrict__ dinv,
                                                  _Float16* __restrict__ xh, int N) {
    const int idx = blockIdx.x * 256 + threadIdx.x;   // over N*16
    if (idx >= N * 16) return;
    const int i = idx >> 4;
    const float dv = dinv[i];
    const floatx4 v = __builtin_nontemporal_load((const floatx4*)&x[(size_t)idx * 4]);
    half4v o;
    o[0] = (_Float16)(dv * v[0]); o[1] = (_Float16)(dv * v[1]);
    o[2] = (_Float16)(dv * v[2]); o[3] = (_Float16)(dv * v[3]);
    *(half4v*)(xh + (size_t)idx * 4) = o;   // temporal: gather1 wants it in L2
}

// ---------------- group-per-row packed fp16 gather ----------------
// X: fp16 rows of 128B, row N = zeros. Wave handles 8 rows: group g (8
// lanes) owns row wave*8+g; lane owns a fixed 16B chunk; edges accumulate
// serially in-lane -> zero reduction. ssrc holds NODE indices (<<7 = byte
// offset). Loop bound is PER-GROUP (exec-masked divergence): __shfl only
// reads same-group lanes, which are active exactly when the group is.

template <bool HALF_OUT, int FOUT, bool BIAS>
__global__ __launch_bounds__(256) void k_gather8(const _Float16* __restrict__ X,
                                                 const float* __restrict__ dinv,
                                                 const int* __restrict__ rstart,
                                                 const int* __restrict__ cnt,
                                                 const int* __restrict__ ssrc,
                                                 const float* __restrict__ bias,
                                                 void* __restrict__ outv,
                                                 int N) {
    const int wave = (blockIdx.x * 256 + threadIdx.x) >> 6;
    const int lane = threadIdx.x & 63;
    const int g = lane >> 3, sub = lane & 7;
    const int r = wave * 8 + g;
    const int rc = min(r, N - 1);
    const int st = rstart[rc];
    const int total = cnt[rc];             // self-inclusive, >= 1 (uniform per group)
    const char* Xb = (const char*)X;
    half2v acc2[4] = {half2v{0, 0}, half2v{0, 0}, half2v{0, 0}, half2v{0, 0}};
    for (int base = 0; base < total; base += 8) {
        const int idx = base + sub;
        int myN = ssrc[st + min(idx, total - 1)];
        myN = (idx < total) ? myN : N;     // OOB tail -> zero row
        const int myO = myN << 7;          // 128B rows
#pragma unroll
        for (int jj = 0; jj < 8; ++jj) {
            const int off = __shfl(myO, g * 8 + jj);
            const half8 hv = *(const half8*)(Xb + off + (sub << 4));
            const half2v* h2 = (const half2v*)&hv;
            acc2[0] += h2[0]; acc2[1] += h2[1];
            acc2[2] += h2[2]; acc2[3] += h2[3];
        }
    }
    if (r >= N) return;
    const float dv = dinv[r];
    float acc[8];
#pragma unroll
    for (int k = 0; k < 8; ++k) acc[k] = (float)acc2[k >> 1][k & 1] * dv;
    if (HALF_OUT) {
        half8 o;
#pragma unroll
        for (int k = 0; k < 8; ++k) o[k] = (_Float16)acc[k];
        *(half8*)((_Float16*)outv + ((size_t)r << 6) + (sub << 3)) = o;  // re-read by mlp: temporal
    } else {
        const int f0 = sub * 8;
        if (f0 < FOUT) {
            if (BIAS) {
                float4 bb0 = *(const float4*)&bias[f0];
                float4 bb1 = *(const float4*)&bias[f0 + 4];
                acc[0] += bb0.x; acc[1] += bb0.y; acc[2] += bb0.z; acc[3] += bb0.w;
                acc[4] += bb1.x; acc[5] += bb1.y; acc[6] += bb1.z; acc[7] += bb1.w;
            }
            float* op = (float*)outv + (size_t)r * FOUT + f0;
            const floatx4 o0 = {acc[0], acc[1], acc[2], acc[3]};
            const floatx4 o1 = {acc[4], acc[5], acc[6], acc[7]};
            __builtin_nontemporal_store(o0, (floatx4*)op);      // out: write-once
            __builtin_nontemporal_store(o1, (floatx4*)(op + 4));
        }
    }
}

// ---------------- fused MFMA MLP: t -> h (regs) -> yh (128B rows) ----------------

__global__ __launch_bounds__(256, 3) void k_mlp(const _Float16* __restrict__ th,
                                                const _Float16* __restrict__ w1f,
                                                const float* __restrict__ b1,
                                                const _Float16* __restrict__ w2f,
                                                const float* __restrict__ dinv,
                                                _Float16* __restrict__ yh, int N) {
    __shared__ _Float16 hbuf[4][16 * 128];  // 16 KB
    const int tid = threadIdx.x;
    const int wave = tid >> 6, lane = tid & 63;
    const int quad = lane >> 4, col = lane & 15;
    const int row0 = blockIdx.x * 64 + wave * 16;
    const int arow = min(row0 + col, N - 1);
    // th is dead after this kernel -> nontemporal (frees L2 for yh/ssrc)
    const half8 a0 = __builtin_nontemporal_load((const half8*)(th + ((size_t)arow << 6) + quad * 8));
    const half8 a1 = __builtin_nontemporal_load((const half8*)(th + ((size_t)arow << 6) + 32 + quad * 8));
    floatx4 c[8];
#pragma unroll
    for (int nt = 0; nt < 8; ++nt) {
        c[nt] = (floatx4){0.f, 0.f, 0.f, 0.f};
        const half8 bb0 = *(const half8*)(w1f + (size_t)((nt * 2 + 0) * 64 + lane) * 8);
        const half8 bb1 = *(const half8*)(w1f + (size_t)((nt * 2 + 1) * 64 + lane) * 8);
        c[nt] = __builtin_amdgcn_mfma_f32_16x16x32_f16(a0, bb0, c[nt], 0, 0, 0);
        c[nt] = __builtin_amdgcn_mfma_f32_16x16x32_f16(a1, bb1, c[nt], 0, 0, 0);
    }
    _Float16* hb = hbuf[wave];
#pragma unroll
    for (int nt = 0; nt < 8; ++nt) {
        const float bv = b1[nt * 16 + col];
#pragma unroll
        for (int reg = 0; reg < 4; ++reg) {
            const int rr = quad * 4 + reg;
            const int hcol = nt * 16 + col;
            const int chunk = ((hcol >> 3) ^ rr) & 15;
            hb[rr * 128 + chunk * 8 + (hcol & 7)] =
                (_Float16)fmaxf(c[nt][reg] + bv, 0.f);
        }
    }
    __syncthreads();
    half8 a2[4];
#pragma unroll
    for (int kk = 0; kk < 4; ++kk) {
        const int chunk = ((kk * 4 + quad) ^ col) & 15;
        a2[kk] = *(const half8*)(hb + col * 128 + chunk * 8);
    }
    floatx4 c2[3];
#pragma unroll
    for (int nt = 0; nt < 3; ++nt) {
        c2[nt] = (floatx4){0.f, 0.f, 0.f, 0.f};
#pragma unroll
        for (int kk = 0; kk < 4; ++kk) {
            const half8 bb = *(const half8*)(w2f + (size_t)((nt * 4 + kk) * 64 + lane) * 8);
            c2[nt] = __builtin_amdgcn_mfma_f32_16x16x32_f16(a2[kk], bb, c2[nt], 0, 0, 0);
        }
    }
#pragma unroll
    for (int reg = 0; reg < 4; ++reg) {
        const int gr = row0 + quad * 4 + reg;
        const float dvr = dinv[min(gr, N - 1)];
#pragma unroll
        for (int nt = 0; nt < 3; ++nt) {
            const int cc = nt * 16 + col;
            if (gr < N && cc < CLS)
                yh[((size_t)gr << 6) + cc] = (_Float16)(c2[nt][reg] * dvr);
        }
    }
    // zero pad cols 40..63 (12 dwords per row)
    for (int i = lane; i < 16 * 12; i += 64) {
        const int row = row0 + i / 12;
        if (row < N)
            ((unsigned*)(yh + ((size_t)row << 6)))[20 + i % 12] = 0u;
    }
}

// ---------------- launch ----------------

extern "C" void kernel_launch(void* const* d_in, const int* in_sizes, int n_in,
                              void* d_out, int out_size, void* d_ws, size_t ws_size,
                              hipStream_t stream) {
    const float* x  = (const float*)d_in[0];
    const int*   ei = (const int*)d_in[1];   // [2][E]
    const float* W1 = (const float*)d_in[2];
    const float* b1 = (const float*)d_in[3];
    const float* W2 = (const float*)d_in[4];
    const float* b2 = (const float*)d_in[5];
    float* out = (float*)d_out;

    const int N = in_sizes[0] / FIN;
    const int E = in_sizes[1] / 2;
    const int NB = (N + 255) >> 8;
    const int per_wg = (E + NWG_P - 1) / NWG_P;

    char* p = (char*)d_ws;
    auto alloc = [&](size_t bytes) {
        char* q = p;
        p += (bytes + 255) & ~(size_t)255;   // keep every array 256B-aligned
        return q;
    };
    float* dinv    = (float*)alloc((size_t)N * 4);
    _Float16* th   = (_Float16*)alloc((size_t)(N + 1) * 128);  // 128B rows
    _Float16* xh   = (_Float16*)alloc((size_t)(N + 1) * 128);  // 128B rows
    _Float16* yh   = (_Float16*)alloc((size_t)(N + 1) * 128);  // 128B rows
    int* cnt       = (int*)alloc((size_t)N * 4);
    int* rstart    = (int*)alloc((size_t)N * 4);
    int* ssrc      = (int*)alloc(((size_t)E + (size_t)NB_MAX * 256) * 4);
    int* cntmat    = (int*)alloc((size_t)NB_MAX * NWG_P * 4);
    int* btot      = (int*)alloc((size_t)NB_MAX * 4);
    int* bbase     = (int*)alloc((size_t)NB_MAX * 4);
    int* gcur      = (int*)alloc(256);
    unsigned* tmp  = (unsigned*)alloc(((size_t)E + (size_t)NB_MAX * 256) * 4);
    _Float16* w1f  = (_Float16*)alloc(8192 * 2);
    _Float16* w2f  = (_Float16*)alloc(6144 * 2);

    dim3 blk(256);
    // CSR build + (prep/zrows/gcur in k_cnt's 2 extra blocks)
    hipLaunchKernelGGL(k_cnt,    dim3(NWG_P + 2), dim3(1024), 0, stream,
                       ei + E, cntmat, E, NB, per_wg, W1, W2, w1f, w2f, xh, yh, gcur, N);
    hipLaunchKernelGGL(k_balloc, dim3(NB), blk, 0, stream, cntmat, bbase, btot, gcur);
    hipLaunchKernelGGL(k_scat,   dim3(NWG_P), dim3(1024), 0, stream, ei, cntmat, bbase, tmp, E, NB, per_wg);
    hipLaunchKernelGGL(k_p2,     dim3(NB), blk, 0, stream, tmp, bbase, btot, rstart, cnt, dinv, ssrc, N);
    // layer 1: prescale -> group-per-row gather (fp16 out, 128B rows)
    hipLaunchKernelGGL(k_prescale, dim3((N * 16 + 255) / 256), blk, 0, stream, x, dinv, xh, N);
    hipLaunchKernelGGL((k_gather8<true, FIN, false>), dim3((N + 31) / 32), blk, 0, stream,
                       xh, dinv, rstart, cnt, ssrc, (const float*)nullptr, (void*)th, N);
    // fused MFMA MLP: t -> h -> yh (128B rows, cols 40..63 zeroed)
    hipLaunchKernelGGL(k_mlp, dim3((N + 63) / 64), blk, 0, stream, th, w1f, b1, w2f, dinv, yh, N);
    // layer 2 aggregate + bias -> out
    hipLaunchKernelGGL((k_gather8<false, CLS, true>), dim3((N + 31) / 32), blk, 0, stream,
                       yh, dinv, rstart, cnt, ssrc, b2, (void*)out, N);
}